// Round 2
// baseline (15.584 us; speedup 1.0000x reference)
//
#include <hip/hip_runtime.h>
#include <hip/hip_bf16.h>

// Embedding lookup: out[row, :] = weight[idx[row], :]
//   idxes:  [8192] int32
//   weight: [50257, 1024] float32
//   out:    [8192, 1024] float32
//
// Memory-bound gather. 2048 blocks x 256 threads; each block copies 4 rows.
// Each thread issues 4 independent float4 gather loads (ILP to hide HBM
// latency), then 4 coalesced float4 stores.

#define FEATURES       1024
#define N_ROWS         (4 * 2048)
#define ROWS_PER_BLOCK 4
#define THREADS        (FEATURES / 4)   // 256: one float4 lane per column group

__global__ void __launch_bounds__(THREADS)
Embedding_59124519797196_kernel(const int* __restrict__ idx,
                                const float* __restrict__ weight,
                                float* __restrict__ out) {
    const int t    = threadIdx.x;                    // 0..255
    const int base = blockIdx.x * ROWS_PER_BLOCK;    // first row of this block

    // Block-uniform index loads (compiler can scalarize these).
    int src[ROWS_PER_BLOCK];
#pragma unroll
    for (int i = 0; i < ROWS_PER_BLOCK; ++i)
        src[i] = idx[base + i];

    // Issue all gather loads before any store -> 4 loads in flight per thread.
    float4 v[ROWS_PER_BLOCK];
#pragma unroll
    for (int i = 0; i < ROWS_PER_BLOCK; ++i)
        v[i] = reinterpret_cast<const float4*>(weight + (size_t)src[i] * FEATURES)[t];

#pragma unroll
    for (int i = 0; i < ROWS_PER_BLOCK; ++i)
        reinterpret_cast<float4*>(out + (size_t)(base + i) * FEATURES)[t] = v[i];
}

extern "C" void kernel_launch(void* const* d_in, const int* in_sizes, int n_in,
                              void* d_out, int out_size, void* d_ws, size_t ws_size,
                              hipStream_t stream) {
    const int*   idx    = (const int*)d_in[0];
    const float* weight = (const float*)d_in[1];
    float*       out    = (float*)d_out;

    dim3 grid(N_ROWS / ROWS_PER_BLOCK);  // 2048
    dim3 block(THREADS);                 // 256

    Embedding_59124519797196_kernel<<<grid, block, 0, stream>>>(idx, weight, out);
}

// Round 4
// 13.978 us; speedup vs baseline: 1.1149x; 1.1149x over previous
//
#include <hip/hip_runtime.h>
#include <hip/hip_bf16.h>

// Embedding lookup: out[row, :] = weight[idx[row], :]
//   idxes:  [8192] int32
//   weight: [50257, 1024] float32  (~206 MB: fits L3)
//   out:    [8192, 1024] float32   (33.5 MB, write-once)
//
// Memory-bound gather. 1024 blocks x 256 threads; each block copies 8 rows.
// 8 independent 16B gather loads in flight per thread (MLP for the
// random-row L2-miss path), then 8 nontemporal 16B stores (bypass L2
// allocation for the write-once output stream).

#define FEATURES       1024
#define N_ROWS         (4 * 2048)
#define ROWS_PER_BLOCK 8
#define THREADS        (FEATURES / 4)   // 256: one 16B lane per column group

typedef float f32x4 __attribute__((ext_vector_type(4)));

__global__ void __launch_bounds__(THREADS)
Embedding_59124519797196_kernel(const int* __restrict__ idx,
                                const float* __restrict__ weight,
                                float* __restrict__ out) {
    const int t    = threadIdx.x;                    // 0..255
    const int base = blockIdx.x * ROWS_PER_BLOCK;    // first row of this block

    // Block-uniform index loads (scalarizable).
    int src[ROWS_PER_BLOCK];
#pragma unroll
    for (int i = 0; i < ROWS_PER_BLOCK; ++i)
        src[i] = idx[base + i];

    // Issue all gather loads before any store -> 8 loads in flight per thread.
    f32x4 v[ROWS_PER_BLOCK];
#pragma unroll
    for (int i = 0; i < ROWS_PER_BLOCK; ++i)
        v[i] = reinterpret_cast<const f32x4*>(weight + (size_t)src[i] * FEATURES)[t];

    // Nontemporal stores: output is never re-read; don't allocate in L2.
#pragma unroll
    for (int i = 0; i < ROWS_PER_BLOCK; ++i)
        __builtin_nontemporal_store(
            v[i], reinterpret_cast<f32x4*>(out + (size_t)(base + i) * FEATURES) + t);
}

extern "C" void kernel_launch(void* const* d_in, const int* in_sizes, int n_in,
                              void* d_out, int out_size, void* d_ws, size_t ws_size,
                              hipStream_t stream) {
    const int*   idx    = (const int*)d_in[0];
    const float* weight = (const float*)d_in[1];
    float*       out    = (float*)d_out;

    dim3 grid(N_ROWS / ROWS_PER_BLOCK);  // 1024
    dim3 block(THREADS);                 // 256

    Embedding_59124519797196_kernel<<<grid, block, 0, stream>>>(idx, weight, out);
}